// Round 2
// baseline (1146.158 us; speedup 1.0000x reference)
//
#include <hip/hip_runtime.h>
#include <hip/hip_bf16.h>

// DFFN fused implementation. R8: de-stall k1.
// R7 counters: k1 = 199.7us, VALUBusy 41%, MfmaUtil 5.4%, HBM 10.5%, 6.29M
// bank-conflict cycles -> latency-bound. Two fixes, math bit-identical:
//  (1) circ-conv phase: y column (64 vals, per-thread-disjoint) loaded ONCE
//      into registers; K row streamed as float4 (L1-hot); inner loop is pure
//      VALU (was 512 scalar ds_read_u16/thread interleaved with FMAs).
//  (2) xs tiles: stride 72->64 halfwords + XOR swizzle (c ^ ((row&7)<<3))
//      -> MFMA-phase ds_read_b128 conflict-free (was ~8-way).
// Pipeline: proj_in(1x1, MFMA hi/lo bf16 = fp32-accurate) -> per-channel 8x8
// circular conv (== rfft2*filter*irfft2 on flat-reshaped "patches" = 1x64
// column runs) -> dw3x3 -> GELU gate -> proj_out(1x1, MFMA bf16).
// Intermediate s: chunk-blocked bf16 [b][c2/8][h][w][8ch] (R7).

#define BATCH 4
#define CIN   64
#define C2    256
#define HH    256
#define WW    256
#define HW    (HH*WW)

using bf16 = __hip_bfloat16;
typedef short bf16x8 __attribute__((ext_vector_type(8)));
typedef float f32x4  __attribute__((ext_vector_type(4)));

__device__ __forceinline__ unsigned f2bf_bits(float v){
    unsigned u = __float_as_uint(v);
    return (u + 0x7fffu + ((u >> 16) & 1u)) >> 16;          // RNE
}
__device__ __forceinline__ float bfbits2f(unsigned hu){ return __uint_as_float(hu << 16); }

__device__ __forceinline__ void unpack8(uint4 v, float* f) {
    unsigned a0 = v.x, a1 = v.y, a2 = v.z, a3 = v.w;
    f[0] = __uint_as_float(a0 << 16); f[1] = __uint_as_float(a0 & 0xffff0000u);
    f[2] = __uint_as_float(a1 << 16); f[3] = __uint_as_float(a1 & 0xffff0000u);
    f[4] = __uint_as_float(a2 << 16); f[5] = __uint_as_float(a2 & 0xffff0000u);
    f[6] = __uint_as_float(a3 << 16); f[7] = __uint_as_float(a3 & 0xffff0000u);
}

// ---------------------------------------------------------------------------
// K0: (a) per-channel 8x8 circular-conv kernel from the rfft2 filter;
//     (b) hi/lo bf16 split of w_in into B-operand tables whi/wlo [c2][cin];
//     (c) bf16 w_out table wob [c_out][128] for k2's MFMA A-frags.
// ---------------------------------------------------------------------------
__global__ void k_precompute(const float* __restrict__ F,
                             const float* __restrict__ w_in,
                             const float* __restrict__ w_out,
                             float* __restrict__ Kc,
                             unsigned short* __restrict__ whi,
                             unsigned short* __restrict__ wlo,
                             unsigned short* __restrict__ wob)
{
    const int c = threadIdx.x;                   // 256 threads = 256 channels
    const float R = 0.7071067811865476f;
    const float C8[8] = {1.f, R, 0.f, -R, -1.f, -R, 0.f, R};
    const float S8[8] = {0.f, R, 1.f, R, 0.f, -R, -1.f, -R};

    // (b) w_in split
    for (int k = 0; k < 64; ++k) {
        float v = w_in[c*64 + k];
        unsigned hu = f2bf_bits(v);
        whi[c*64 + k] = (unsigned short)hu;
        wlo[c*64 + k] = (unsigned short)f2bf_bits(v - bfbits2f(hu));
    }
    // (c) w_out bf16 table
    for (int e = c; e < 64*128; e += 256)
        wob[e] = (unsigned short)f2bf_bits(w_out[e]);

    // (a) conv kernel
    float Fv[8][5];
    for (int u = 0; u < 8; ++u)
        for (int v = 0; v < 5; ++v)
            Fv[u][v] = F[c*40 + u*5 + v];

    float ReG[5][8], ImG[5][8];
    for (int v = 0; v < 5; ++v)
        for (int m = 0; m < 8; ++m) {
            float re = 0.f, im = 0.f;
            for (int u = 0; u < 8; ++u) {
                int idx = (u*m) & 7;
                re += Fv[u][v] * C8[idx];
                im += Fv[u][v] * S8[idx];
            }
            ReG[v][m] = re * 0.125f;
            ImG[v][m] = im * 0.125f;
        }

    for (int m = 0; m < 8; ++m)
        for (int n = 0; n < 8; ++n) {
            float acc = 0.f;
            for (int v = 0; v < 5; ++v) {
                float wv = (v == 0 || v == 4) ? 0.125f : 0.25f;
                int idx = (v*n) & 7;
                acc += wv * (ReG[v][m]*C8[idx] - ImG[v][m]*S8[idx]);
            }
            Kc[c*64 + m*8 + n] = acc;
        }
}

// ---------------------------------------------------------------------------
// K1: per (b, h, 64-col run): proj_in via MFMA (m=px16, n=c2, k=cin) with
// hi/lo bf16 split, then register-resident VALU circular conv, bf16
// chunk-blocked store s[b][c2/8][h][w][8ch].
// R8: XOR-swizzled xs (conflict-free A-frag reads); conv y in VGPRs.
// ---------------------------------------------------------------------------
__global__ __launch_bounds__(256) void k1_proj_circ(
    const float* __restrict__ x,
    const unsigned short* __restrict__ whi,
    const unsigned short* __restrict__ wlo,
    const float* __restrict__ b_in, const float* __restrict__ Kc,
    bf16* __restrict__ s)
{
    __shared__ __align__(16) unsigned short xs_hi[64*64];   // 8 KB, swizzled
    __shared__ __align__(16) unsigned short xs_lo[64*64];   // 8 KB, swizzled
    __shared__ __align__(16) unsigned short ysT[64*258];    // 32.25 KB

    const int tid = threadIdx.x;
    const int bid = blockIdx.x;
    const int run = bid & 3;
    const int h   = (bid >> 2) & 255;
    const int b   = bid >> 10;

    const float* xb = x + (long)b * CIN * HW + h * WW + run * 64;

    // stage x tile (64 cin x 64 px), hi/lo bf16 split, transposed [px][cin],
    // XOR-swizzled: element (row=px, c) at halfword row*64 + (c ^ ((row&7)<<3)).
#pragma unroll
    for (int i = 0; i < 16; ++i) {
        int e = i*256 + tid;
        int c = e >> 6, col = e & 63;
        float v = xb[(long)c * HW + col];
        unsigned hu = f2bf_bits(v);
        unsigned lu = f2bf_bits(v - bfbits2f(hu));
        const int sw = col*64 + (c ^ ((col & 7) << 3));
        xs_hi[sw] = (unsigned short)hu;
        xs_lo[sw] = (unsigned short)lu;
    }
    __syncthreads();

    const int wv = tid >> 6, lane = tid & 63;
    const int quad = lane >> 4, n16 = lane & 15;

    // wave wv handles c2 in [wv*64, wv*64+64)
    for (int nt = 0; nt < 4; ++nt) {                 // rolled: low pressure
        const int c2 = wv*64 + nt*16 + n16;
        f32x4 acc[4];
#pragma unroll
        for (int mt = 0; mt < 4; ++mt) acc[mt] = (f32x4){0.f,0.f,0.f,0.f};

#pragma unroll
        for (int k = 0; k < 2; ++k) {
            const bf16x8 bh = *(const bf16x8*)&whi[c2*64 + k*32 + quad*8];
            const bf16x8 bl = *(const bf16x8*)&wlo[c2*64 + k*32 + quad*8];
#pragma unroll
            for (int mt = 0; mt < 4; ++mt) {
                // row = mt*16+n16; 16B slot (k*4+quad) XOR (row&7)
                const int o = (mt*16 + n16)*64 + (((k*4 + quad) ^ (n16 & 7)) << 3);
                const bf16x8 a_h = *(const bf16x8*)&xs_hi[o];
                const bf16x8 a_l = *(const bf16x8*)&xs_lo[o];
                acc[mt] = __builtin_amdgcn_mfma_f32_16x16x32_bf16(a_h, bh, acc[mt], 0, 0, 0);
                acc[mt] = __builtin_amdgcn_mfma_f32_16x16x32_bf16(a_l, bh, acc[mt], 0, 0, 0);
                acc[mt] = __builtin_amdgcn_mfma_f32_16x16x32_bf16(a_h, bl, acc[mt], 0, 0, 0);
            }
        }
        const float bv = b_in[c2];
#pragma unroll
        for (int mt = 0; mt < 4; ++mt)
#pragma unroll
            for (int r = 0; r < 4; ++r) {
                int u = mt*16 + quad*4 + r;          // D row = quad*4 + reg
                ysT[u*258 + c2] = (unsigned short)f2bf_bits(acc[mt][r] + bv);
            }
    }
    __syncthreads();

    // circular conv: thread = channel tid. Column tid of ysT is private to
    // this thread (reads and writes), so no barrier needed inside.
    // R8: y loaded once into registers; K row streamed per (a,m) as float4.
    float y[64];
#pragma unroll
    for (int u = 0; u < 64; ++u)
        y[u] = bfbits2f((unsigned)ysT[u*258 + tid]);

    const float* Kp = Kc + tid*64;
#pragma unroll
    for (int a = 0; a < 8; ++a) {
        float o8[8];
#pragma unroll
        for (int bb = 0; bb < 8; ++bb) o8[bb] = 0.f;
#pragma unroll
        for (int m = 0; m < 8; ++m) {
            const int r = (a - m) & 7;
            const float4 ka = *(const float4*)&Kp[m*8];
            const float4 kb = *(const float4*)&Kp[m*8 + 4];
            const float kk[8] = {ka.x, ka.y, ka.z, ka.w, kb.x, kb.y, kb.z, kb.w};
#pragma unroll
            for (int n = 0; n < 8; ++n)
#pragma unroll
                for (int bb = 0; bb < 8; ++bb)
                    o8[bb] += kk[n] * y[r*8 + ((bb - n) & 7)];
        }
#pragma unroll
        for (int bb = 0; bb < 8; ++bb)
            ysT[(a*8 + bb)*258 + tid] = (unsigned short)f2bf_bits(o8[bb]);
    }
    __syncthreads();

    // store: chunk-blocked layout s[b][chunk=c2/8][h][w][8ch]
    // lane = px u -> 64 lanes x 16B = 1KB contiguous per (chunk, pass).
    const int u   = tid & 63;
    const int rg2 = tid >> 6;          // 0..3
#pragma unroll
    for (int pass = 0; pass < 8; ++pass) {
        const int chunk = pass*4 + rg2;                       // 0..31
        const unsigned* yp = (const unsigned*)&ysT[u*258 + chunk*8];
        uint4 val = make_uint4(yp[0], yp[1], yp[2], yp[3]);
        *(uint4*)(s + ((((long)(b*32 + chunk)*HH + h)*WW) + run*64 + u)*8) = val;
    }
}

// ---------------------------------------------------------------------------
// K2: per (b, h, run of 64 px): dw3x3 + bias -> GELU gate -> MFMA proj_out.
// Phase 1: thread = (px=lane, chunk-pair of 8 ch), 4 tasks; 18 x 16B global
//   loads per task, fully coalesced (chunk wave-uniform, wx lane-consecutive
//   -> 1KB/wave-load); g packed bf16 into LDS gs[px][c] stride 136.
// Phase 2: MFMA 16x16x32_bf16, m=c_out(64), n=px(64), k=c(128). Wave rg owns
//   px-tile rg*16; A-frags from ws-resident wob table, B-frags ds_read_b128.
// ---------------------------------------------------------------------------
__global__ __launch_bounds__(256) void k2_dw_gelu_out(
    const bf16* __restrict__ s, const float* __restrict__ w_dw,
    const float* __restrict__ b_dw,
    const unsigned short* __restrict__ wob,
    const float* __restrict__ b_out, float* __restrict__ out)
{
    __shared__ __align__(16) unsigned short gs[64*136];   // 17 KB, [px][c]

    const int tid = threadIdx.x;
    const int l   = ((blockIdx.x & 7) << 9) | (blockIdx.x >> 3);  // XCD swizzle
    const int run = l & 3;
    const int h   = (l >> 2) & 255;
    const int b   = l >> 10;
    const int wl  = tid & 63, rg = tid >> 6;
    const int w   = run*64 + wl;

#pragma unroll
    for (int i = 0; i < 4; ++i) {
        const int chunk = __builtin_amdgcn_readfirstlane(rg + 4*i);   // 0..15, uniform
        const int c0 = chunk*8;                                        // 0..120
        const bf16* pb1 = s + (long)(b*32 + chunk     ) * HW * 8;
        const bf16* pb2 = s + (long)(b*32 + chunk + 16) * HW * 8;

        float t1[8], t2[8];
#pragma unroll
        for (int j = 0; j < 8; ++j) { t1[j] = b_dw[c0+j]; t2[j] = b_dw[c0+128+j]; }

#pragma unroll
        for (int dy = 0; dy < 3; ++dy) {
            const int hy = h + dy - 1;
            if ((unsigned)hy >= HH) continue;          // wave-uniform
#pragma unroll
            for (int dx = 0; dx < 3; ++dx) {
                const int wx = w + dx - 1;
                if ((unsigned)wx < WW) {               // diverges only at image edge
                    const int off = (hy*WW + wx) << 3; // element offset, fits int
                    uint4 v1 = *(const uint4*)(pb1 + off);
                    uint4 v2 = *(const uint4*)(pb2 + off);
                    float f1[8], f2[8];
                    unpack8(v1, f1); unpack8(v2, f2);
#pragma unroll
                    for (int j = 0; j < 8; ++j) {
                        t1[j] += f1[j] * w_dw[(c0+j)*9       + dy*3 + dx];
                        t2[j] += f2[j] * w_dw[(c0+128+j)*9   + dy*3 + dx];
                    }
                }
            }
        }
        // GELU(t1)*t2, exact erf; pack to bf16 pairs, store [px=wl][c0..c0+7]
        unsigned r4[4];
#pragma unroll
        for (int j = 0; j < 4; ++j) {
            float ga = t1[2*j]   * 0.5f * (1.0f + erff(t1[2*j]   * 0.7071067811865476f)) * t2[2*j];
            float gb = t1[2*j+1] * 0.5f * (1.0f + erff(t1[2*j+1] * 0.7071067811865476f)) * t2[2*j+1];
            r4[j] = f2bf_bits(ga) | (f2bf_bits(gb) << 16);
        }
        *(uint4*)&gs[wl*136 + c0] = make_uint4(r4[0], r4[1], r4[2], r4[3]);
    }
    __syncthreads();

    // Phase 2: MFMA proj_out. Wave rg -> px-tile rg*16..+15.
    const int quad = wl >> 4, n16 = wl & 15;
    const int px   = rg*16 + n16;

    f32x4 acc[4];                                  // mt = c_out tile
#pragma unroll
    for (int mt = 0; mt < 4; ++mt) acc[mt] = (f32x4){0.f,0.f,0.f,0.f};

#pragma unroll
    for (int ks = 0; ks < 4; ++ks) {
        const bf16x8 bfrag = *(const bf16x8*)&gs[px*136 + ks*32 + quad*8];
#pragma unroll
        for (int mt = 0; mt < 4; ++mt) {
            const bf16x8 afrag = *(const bf16x8*)&wob[(mt*16 + n16)*128 + ks*32 + quad*8];
            acc[mt] = __builtin_amdgcn_mfma_f32_16x16x32_bf16(afrag, bfrag, acc[mt], 0, 0, 0);
        }
    }

    // D: col=lane&15 = n = px-within-tile, row = quad*4+r = c_out-within-tile
    float* op = out + (long)b * CIN * HW + h * WW + run*64 + rg*16 + n16;
#pragma unroll
    for (int mt = 0; mt < 4; ++mt)
#pragma unroll
        for (int r = 0; r < 4; ++r) {
            const int c_out = mt*16 + quad*4 + r;
            op[(long)c_out * HW] = acc[mt][r] + b_out[c_out];
        }
}

// ---------------------------------------------------------------------------
extern "C" void kernel_launch(void* const* d_in, const int* in_sizes, int n_in,
                              void* d_out, int out_size, void* d_ws, size_t ws_size,
                              hipStream_t stream) {
    const float* x     = (const float*)d_in[0];
    const float* w_in  = (const float*)d_in[1];
    const float* b_in  = (const float*)d_in[2];
    const float* ff    = (const float*)d_in[3];
    const float* w_dw  = (const float*)d_in[4];
    const float* b_dw  = (const float*)d_in[5];
    const float* w_out = (const float*)d_in[6];
    const float* b_out = (const float*)d_in[7];
    float* out = (float*)d_out;

    // d_ws layout: Kc [0,64K) | wob [64K,80K) | s [80K, +128MB)
    float*          Kc  = (float*)d_ws;
    unsigned short* wob = (unsigned short*)((char*)d_ws + 65536);   // 16 KB
    bf16*           s   = (bf16*)((char*)d_ws + 65536 + 16384);

    // whi/wlo in d_out is safe: only k1 reads them, and k1 fully retires
    // (stream order) before k2 begins overwriting d_out.
    unsigned short* whi = (unsigned short*)d_out;       // 32 KB
    unsigned short* wlo = whi + 256*64;                 // 32 KB

    hipLaunchKernelGGL(k_precompute,   dim3(1),    dim3(256), 0, stream,
                       ff, w_in, w_out, Kc, whi, wlo, wob);
    hipLaunchKernelGGL(k1_proj_circ,   dim3(4096), dim3(256), 0, stream,
                       x, whi, wlo, b_in, Kc, s);
    hipLaunchKernelGGL(k2_dw_gelu_out, dim3(4096), dim3(256), 0, stream,
                       s, w_dw, b_dw, wob, b_out, out);
}

// Round 3
// 379.694 us; speedup vs baseline: 3.0186x; 3.0186x over previous
//
#include <hip/hip_runtime.h>
#include <hip/hip_bf16.h>

// DFFN fused implementation. R9: fix k1's conv-phase K-load gather + undo R8's
// I$-thrashing full unroll.
// R8 post-mortem: fully-unrolled 4096-FMA conv body (~40KB code) overflowed
// the 32KB L1I -> perpetual instruction-fetch stalls (VALUBusy 15%, 924us).
// R7 analysis: K loads Kc[tid*64+...] have 256B lane stride -> every scalar
// load is a 64-cache-line gather; 512/thread serialized in L1 -> the real
// stall behind R7's 41% VALUBusy.
// R9: K table transposed to KcT[j=m*8+n][c] -> kk loads lane-coalesced (256B
// contiguous per wave); conv loop m-OUTER (rolled) so each K row loads once
// (64 coalesced scalars/thread, was 512 gathers); a unrolled (static o[]);
// yy reads stay R7's conflict-free ds_read_u16. Code ~5KB, regs ~110.
// Pipeline: proj_in(1x1, MFMA hi/lo bf16 = fp32-accurate) -> per-channel 8x8
// circular conv (== rfft2*filter*irfft2 on flat-reshaped "patches" = 1x64
// column runs) -> dw3x3 -> GELU gate -> proj_out(1x1, MFMA bf16).
// Intermediate s: chunk-blocked bf16 [b][c2/8][h][w][8ch] (R7).

#define BATCH 4
#define CIN   64
#define C2    256
#define HH    256
#define WW    256
#define HW    (HH*WW)

using bf16 = __hip_bfloat16;
typedef short bf16x8 __attribute__((ext_vector_type(8)));
typedef float f32x4  __attribute__((ext_vector_type(4)));

__device__ __forceinline__ unsigned f2bf_bits(float v){
    unsigned u = __float_as_uint(v);
    return (u + 0x7fffu + ((u >> 16) & 1u)) >> 16;          // RNE
}
__device__ __forceinline__ float bfbits2f(unsigned hu){ return __uint_as_float(hu << 16); }

__device__ __forceinline__ void unpack8(uint4 v, float* f) {
    unsigned a0 = v.x, a1 = v.y, a2 = v.z, a3 = v.w;
    f[0] = __uint_as_float(a0 << 16); f[1] = __uint_as_float(a0 & 0xffff0000u);
    f[2] = __uint_as_float(a1 << 16); f[3] = __uint_as_float(a1 & 0xffff0000u);
    f[4] = __uint_as_float(a2 << 16); f[5] = __uint_as_float(a2 & 0xffff0000u);
    f[6] = __uint_as_float(a3 << 16); f[7] = __uint_as_float(a3 & 0xffff0000u);
}

// ---------------------------------------------------------------------------
// K0: (a) per-channel 8x8 circular-conv kernel from the rfft2 filter,
//     stored TRANSPOSED: KcT[j=m*8+n][c]  (coalesced for k1's conv);
//     (b) hi/lo bf16 split of w_in into B-operand tables whi/wlo [c2][cin];
//     (c) bf16 w_out table wob [c_out][128] for k2's MFMA A-frags.
// ---------------------------------------------------------------------------
__global__ void k_precompute(const float* __restrict__ F,
                             const float* __restrict__ w_in,
                             const float* __restrict__ w_out,
                             float* __restrict__ KcT,
                             unsigned short* __restrict__ whi,
                             unsigned short* __restrict__ wlo,
                             unsigned short* __restrict__ wob)
{
    const int c = threadIdx.x;                   // 256 threads = 256 channels
    const float R = 0.7071067811865476f;
    const float C8[8] = {1.f, R, 0.f, -R, -1.f, -R, 0.f, R};
    const float S8[8] = {0.f, R, 1.f, R, 0.f, -R, -1.f, -R};

    // (b) w_in split
    for (int k = 0; k < 64; ++k) {
        float v = w_in[c*64 + k];
        unsigned hu = f2bf_bits(v);
        whi[c*64 + k] = (unsigned short)hu;
        wlo[c*64 + k] = (unsigned short)f2bf_bits(v - bfbits2f(hu));
    }
    // (c) w_out bf16 table
    for (int e = c; e < 64*128; e += 256)
        wob[e] = (unsigned short)f2bf_bits(w_out[e]);

    // (a) conv kernel
    float Fv[8][5];
    for (int u = 0; u < 8; ++u)
        for (int v = 0; v < 5; ++v)
            Fv[u][v] = F[c*40 + u*5 + v];

    float ReG[5][8], ImG[5][8];
    for (int v = 0; v < 5; ++v)
        for (int m = 0; m < 8; ++m) {
            float re = 0.f, im = 0.f;
            for (int u = 0; u < 8; ++u) {
                int idx = (u*m) & 7;
                re += Fv[u][v] * C8[idx];
                im += Fv[u][v] * S8[idx];
            }
            ReG[v][m] = re * 0.125f;
            ImG[v][m] = im * 0.125f;
        }

    for (int m = 0; m < 8; ++m)
        for (int n = 0; n < 8; ++n) {
            float acc = 0.f;
            for (int v = 0; v < 5; ++v) {
                float wv = (v == 0 || v == 4) ? 0.125f : 0.25f;
                int idx = (v*n) & 7;
                acc += wv * (ReG[v][m]*C8[idx] - ImG[v][m]*S8[idx]);
            }
            KcT[(m*8 + n)*256 + c] = acc;        // transposed: [j][channel]
        }
}

// ---------------------------------------------------------------------------
// K1: per (b, h, 64-col run): proj_in via MFMA (m=px16, n=c2, k=cin) with
// hi/lo bf16 split, then VALU circular conv (m-outer, coalesced K loads),
// bf16 chunk-blocked store s[b][c2/8][h][w][8ch].
// ---------------------------------------------------------------------------
__global__ __launch_bounds__(256) void k1_proj_circ(
    const float* __restrict__ x,
    const unsigned short* __restrict__ whi,
    const unsigned short* __restrict__ wlo,
    const float* __restrict__ b_in, const float* __restrict__ KcT,
    bf16* __restrict__ s)
{
    __shared__ __align__(16) unsigned short xs_hi[64*64];   // 8 KB, swizzled
    __shared__ __align__(16) unsigned short xs_lo[64*64];   // 8 KB, swizzled
    __shared__ __align__(16) unsigned short ysT[64*258];    // 32.25 KB

    const int tid = threadIdx.x;
    const int bid = blockIdx.x;
    const int run = bid & 3;
    const int h   = (bid >> 2) & 255;
    const int b   = bid >> 10;

    const float* xb = x + (long)b * CIN * HW + h * WW + run * 64;

    // stage x tile (64 cin x 64 px), hi/lo bf16 split, transposed [px][cin],
    // XOR-swizzled: element (row=px, c) at halfword row*64 + (c ^ ((row&7)<<3)).
#pragma unroll
    for (int i = 0; i < 16; ++i) {
        int e = i*256 + tid;
        int c = e >> 6, col = e & 63;
        float v = xb[(long)c * HW + col];
        unsigned hu = f2bf_bits(v);
        unsigned lu = f2bf_bits(v - bfbits2f(hu));
        const int sw = col*64 + (c ^ ((col & 7) << 3));
        xs_hi[sw] = (unsigned short)hu;
        xs_lo[sw] = (unsigned short)lu;
    }
    __syncthreads();

    const int wv = tid >> 6, lane = tid & 63;
    const int quad = lane >> 4, n16 = lane & 15;

    // wave wv handles c2 in [wv*64, wv*64+64)
    for (int nt = 0; nt < 4; ++nt) {                 // rolled: low pressure
        const int c2 = wv*64 + nt*16 + n16;
        f32x4 acc[4];
#pragma unroll
        for (int mt = 0; mt < 4; ++mt) acc[mt] = (f32x4){0.f,0.f,0.f,0.f};

#pragma unroll
        for (int k = 0; k < 2; ++k) {
            const bf16x8 bh = *(const bf16x8*)&whi[c2*64 + k*32 + quad*8];
            const bf16x8 bl = *(const bf16x8*)&wlo[c2*64 + k*32 + quad*8];
#pragma unroll
            for (int mt = 0; mt < 4; ++mt) {
                // row = mt*16+n16; 16B slot (k*4+quad) XOR (row&7)
                const int o = (mt*16 + n16)*64 + (((k*4 + quad) ^ (n16 & 7)) << 3);
                const bf16x8 a_h = *(const bf16x8*)&xs_hi[o];
                const bf16x8 a_l = *(const bf16x8*)&xs_lo[o];
                acc[mt] = __builtin_amdgcn_mfma_f32_16x16x32_bf16(a_h, bh, acc[mt], 0, 0, 0);
                acc[mt] = __builtin_amdgcn_mfma_f32_16x16x32_bf16(a_l, bh, acc[mt], 0, 0, 0);
                acc[mt] = __builtin_amdgcn_mfma_f32_16x16x32_bf16(a_h, bl, acc[mt], 0, 0, 0);
            }
        }
        const float bv = b_in[c2];
#pragma unroll
        for (int mt = 0; mt < 4; ++mt)
#pragma unroll
            for (int r = 0; r < 4; ++r) {
                int u = mt*16 + quad*4 + r;          // D row = quad*4 + reg
                ysT[u*258 + c2] = (unsigned short)f2bf_bits(acc[mt][r] + bv);
            }
    }
    __syncthreads();

    // circular conv: thread = channel tid. Column tid of ysT is private to
    // this thread (reads and writes), so no barrier needed inside.
    // m-OUTER rolled loop: K row m loaded once, lane-coalesced from KcT.
    float o[64];
#pragma unroll
    for (int i = 0; i < 64; ++i) o[i] = 0.f;

    for (int m = 0; m < 8; ++m) {                    // rolled: keeps code ~5KB
        float kk[8];
#pragma unroll
        for (int n = 0; n < 8; ++n)
            kk[n] = KcT[(m*8 + n)*256 + tid];        // 64 lanes x 4B contiguous
#pragma unroll
        for (int a = 0; a < 8; ++a) {
            const int r = (a - m) & 7;
            float yy[8];
#pragma unroll
            for (int q = 0; q < 8; ++q)
                yy[q] = bfbits2f((unsigned)ysT[(r*8 + q)*258 + tid]);
#pragma unroll
            for (int n = 0; n < 8; ++n)
#pragma unroll
                for (int bb = 0; bb < 8; ++bb)
                    o[a*8 + bb] += kk[n] * yy[(bb - n) & 7];
        }
    }

#pragma unroll
    for (int u = 0; u < 64; ++u)
        ysT[u*258 + tid] = (unsigned short)f2bf_bits(o[u]);
    __syncthreads();

    // store: chunk-blocked layout s[b][chunk=c2/8][h][w][8ch]
    // lane = px u -> 64 lanes x 16B = 1KB contiguous per (chunk, pass).
    const int u   = tid & 63;
    const int rg2 = tid >> 6;          // 0..3
#pragma unroll
    for (int pass = 0; pass < 8; ++pass) {
        const int chunk = pass*4 + rg2;                       // 0..31
        const unsigned* yp = (const unsigned*)&ysT[u*258 + chunk*8];
        uint4 val = make_uint4(yp[0], yp[1], yp[2], yp[3]);
        *(uint4*)(s + ((((long)(b*32 + chunk)*HH + h)*WW) + run*64 + u)*8) = val;
    }
}

// ---------------------------------------------------------------------------
// K2: per (b, h, run of 64 px): dw3x3 + bias -> GELU gate -> MFMA proj_out.
// Phase 1: thread = (px=lane, chunk-pair of 8 ch), 4 tasks; 18 x 16B global
//   loads per task, fully coalesced (chunk wave-uniform, wx lane-consecutive
//   -> 1KB/wave-load); g packed bf16 into LDS gs[px][c] stride 136.
// Phase 2: MFMA 16x16x32_bf16, m=c_out(64), n=px(64), k=c(128). Wave rg owns
//   px-tile rg*16; A-frags from ws-resident wob table, B-frags ds_read_b128.
// ---------------------------------------------------------------------------
__global__ __launch_bounds__(256) void k2_dw_gelu_out(
    const bf16* __restrict__ s, const float* __restrict__ w_dw,
    const float* __restrict__ b_dw,
    const unsigned short* __restrict__ wob,
    const float* __restrict__ b_out, float* __restrict__ out)
{
    __shared__ __align__(16) unsigned short gs[64*136];   // 17 KB, [px][c]

    const int tid = threadIdx.x;
    const int l   = ((blockIdx.x & 7) << 9) | (blockIdx.x >> 3);  // XCD swizzle
    const int run = l & 3;
    const int h   = (l >> 2) & 255;
    const int b   = l >> 10;
    const int wl  = tid & 63, rg = tid >> 6;
    const int w   = run*64 + wl;

#pragma unroll
    for (int i = 0; i < 4; ++i) {
        const int chunk = __builtin_amdgcn_readfirstlane(rg + 4*i);   // 0..15, uniform
        const int c0 = chunk*8;                                        // 0..120
        const bf16* pb1 = s + (long)(b*32 + chunk     ) * HW * 8;
        const bf16* pb2 = s + (long)(b*32 + chunk + 16) * HW * 8;

        float t1[8], t2[8];
#pragma unroll
        for (int j = 0; j < 8; ++j) { t1[j] = b_dw[c0+j]; t2[j] = b_dw[c0+128+j]; }

#pragma unroll
        for (int dy = 0; dy < 3; ++dy) {
            const int hy = h + dy - 1;
            if ((unsigned)hy >= HH) continue;          // wave-uniform
#pragma unroll
            for (int dx = 0; dx < 3; ++dx) {
                const int wx = w + dx - 1;
                if ((unsigned)wx < WW) {               // diverges only at image edge
                    const int off = (hy*WW + wx) << 3; // element offset, fits int
                    uint4 v1 = *(const uint4*)(pb1 + off);
                    uint4 v2 = *(const uint4*)(pb2 + off);
                    float f1[8], f2[8];
                    unpack8(v1, f1); unpack8(v2, f2);
#pragma unroll
                    for (int j = 0; j < 8; ++j) {
                        t1[j] += f1[j] * w_dw[(c0+j)*9       + dy*3 + dx];
                        t2[j] += f2[j] * w_dw[(c0+128+j)*9   + dy*3 + dx];
                    }
                }
            }
        }
        // GELU(t1)*t2, exact erf; pack to bf16 pairs, store [px=wl][c0..c0+7]
        unsigned r4[4];
#pragma unroll
        for (int j = 0; j < 4; ++j) {
            float ga = t1[2*j]   * 0.5f * (1.0f + erff(t1[2*j]   * 0.7071067811865476f)) * t2[2*j];
            float gb = t1[2*j+1] * 0.5f * (1.0f + erff(t1[2*j+1] * 0.7071067811865476f)) * t2[2*j+1];
            r4[j] = f2bf_bits(ga) | (f2bf_bits(gb) << 16);
        }
        *(uint4*)&gs[wl*136 + c0] = make_uint4(r4[0], r4[1], r4[2], r4[3]);
    }
    __syncthreads();

    // Phase 2: MFMA proj_out. Wave rg -> px-tile rg*16..+15.
    const int quad = wl >> 4, n16 = wl & 15;
    const int px   = rg*16 + n16;

    f32x4 acc[4];                                  // mt = c_out tile
#pragma unroll
    for (int mt = 0; mt < 4; ++mt) acc[mt] = (f32x4){0.f,0.f,0.f,0.f};

#pragma unroll
    for (int ks = 0; ks < 4; ++ks) {
        const bf16x8 bfrag = *(const bf16x8*)&gs[px*136 + ks*32 + quad*8];
#pragma unroll
        for (int mt = 0; mt < 4; ++mt) {
            const bf16x8 afrag = *(const bf16x8*)&wob[(mt*16 + n16)*128 + ks*32 + quad*8];
            acc[mt] = __builtin_amdgcn_mfma_f32_16x16x32_bf16(afrag, bfrag, acc[mt], 0, 0, 0);
        }
    }

    // D: col=lane&15 = n = px-within-tile, row = quad*4+r = c_out-within-tile
    float* op = out + (long)b * CIN * HW + h * WW + run*64 + rg*16 + n16;
#pragma unroll
    for (int mt = 0; mt < 4; ++mt)
#pragma unroll
        for (int r = 0; r < 4; ++r) {
            const int c_out = mt*16 + quad*4 + r;
            op[(long)c_out * HW] = acc[mt][r] + b_out[c_out];
        }
}

// ---------------------------------------------------------------------------
extern "C" void kernel_launch(void* const* d_in, const int* in_sizes, int n_in,
                              void* d_out, int out_size, void* d_ws, size_t ws_size,
                              hipStream_t stream) {
    const float* x     = (const float*)d_in[0];
    const float* w_in  = (const float*)d_in[1];
    const float* b_in  = (const float*)d_in[2];
    const float* ff    = (const float*)d_in[3];
    const float* w_dw  = (const float*)d_in[4];
    const float* b_dw  = (const float*)d_in[5];
    const float* w_out = (const float*)d_in[6];
    const float* b_out = (const float*)d_in[7];
    float* out = (float*)d_out;

    // d_ws layout: KcT [0,64K) | wob [64K,80K) | s [80K, +128MB)
    float*          KcT = (float*)d_ws;
    unsigned short* wob = (unsigned short*)((char*)d_ws + 65536);   // 16 KB
    bf16*           s   = (bf16*)((char*)d_ws + 65536 + 16384);

    // whi/wlo in d_out is safe: only k1 reads them, and k1 fully retires
    // (stream order) before k2 begins overwriting d_out.
    unsigned short* whi = (unsigned short*)d_out;       // 32 KB
    unsigned short* wlo = whi + 256*64;                 // 32 KB

    hipLaunchKernelGGL(k_precompute,   dim3(1),    dim3(256), 0, stream,
                       ff, w_in, w_out, KcT, whi, wlo, wob);
    hipLaunchKernelGGL(k1_proj_circ,   dim3(4096), dim3(256), 0, stream,
                       x, whi, wlo, b_in, KcT, s);
    hipLaunchKernelGGL(k2_dw_gelu_out, dim3(4096), dim3(256), 0, stream,
                       s, w_dw, b_dw, wob, b_out, out);
}

// Round 6
// 375.965 us; speedup vs baseline: 3.0486x; 1.0099x over previous
//
#include <hip/hip_runtime.h>
#include <hip/hip_bf16.h>

// DFFN fused implementation. R12 = R10 with the GELU bug fixed.
// R11 post-mortem: absmax 4.15e-3 failure was the A&S erf-poly rewrite
// dropping the 1/sqrt(2) argument scale (computed erf(v), not erf(v/sqrt2)).
// k0-parallelize and k1-LDS-union were bit-identical and are kept:
//  (1) k0 parallelized: 16 blocks, flat coalesced w_in-split/wob; conv-kernel
//      build spread over 8 blocks (was 1 workgroup, ~40us).
//  (2) k1 LDS union: xs_hi/xs_lo (16KB) dead after proj MFMAs; all 4 nt-tiles
//      accumulated in regs (64 VGPR), barrier, ysT overwrites xs. LDS 49.6KB
//      -> 33KB => 4 blocks/CU (was 3) to feed the VALU-issue-bound conv
//      (VALUBusy 72%). launch_bounds(256,4) pins VGPR <= 128.
//  (3) k2 GELU: A&S 7.1.26 poly with CORRECT z = v/sqrt2 (|eps|<=1.5e-7,
//      invisible under bf16 storage quantum), branchless ~15 instrs.
// Pipeline: proj_in(1x1, MFMA hi/lo bf16 = fp32-accurate) -> per-channel 8x8
// circular conv (== rfft2*filter*irfft2 on flat-reshaped "patches" = 1x64
// column runs) -> dw3x3 -> GELU gate -> proj_out(1x1, MFMA bf16).
// Intermediate s: chunk-blocked bf16 [b][c2/8][h][w][8ch] (R7).

#define BATCH 4
#define CIN   64
#define C2    256
#define HH    256
#define WW    256
#define HW    (HH*WW)

using bf16 = __hip_bfloat16;
typedef short bf16x8 __attribute__((ext_vector_type(8)));
typedef float f32x4  __attribute__((ext_vector_type(4)));

__device__ __forceinline__ unsigned f2bf_bits(float v){
    unsigned u = __float_as_uint(v);
    return (u + 0x7fffu + ((u >> 16) & 1u)) >> 16;          // RNE
}
__device__ __forceinline__ float bfbits2f(unsigned hu){ return __uint_as_float(hu << 16); }

__device__ __forceinline__ void unpack8(uint4 v, float* f) {
    unsigned a0 = v.x, a1 = v.y, a2 = v.z, a3 = v.w;
    f[0] = __uint_as_float(a0 << 16); f[1] = __uint_as_float(a0 & 0xffff0000u);
    f[2] = __uint_as_float(a1 << 16); f[3] = __uint_as_float(a1 & 0xffff0000u);
    f[4] = __uint_as_float(a2 << 16); f[5] = __uint_as_float(a2 & 0xffff0000u);
    f[6] = __uint_as_float(a3 << 16); f[7] = __uint_as_float(a3 & 0xffff0000u);
}

// GELU(v) = 0.5*v*(1+erf(v/sqrt2)), erf via A&S 7.1.26 (|eps| <= 1.5e-7).
__device__ __forceinline__ float gelu_exact(float v){
    float z  = v * 0.7071067811865476f;          // the R11 bug: this was missing
    float ax = fabsf(z);
    float t  = 1.0f / fmaf(0.3275911f, ax, 1.0f);
    float p  = t * fmaf(t, fmaf(t, fmaf(t, fmaf(t, 1.061405429f, -1.453152027f),
                                        1.421413741f), -0.284496736f), 0.254829592f);
    float e  = __expf(-ax*ax);
    float er = fmaf(-p, e, 1.0f);                // erf(|z|)
    er = copysignf(er, z);
    return 0.5f * v * (1.0f + er);
}

// ---------------------------------------------------------------------------
// K0 (16 blocks): (a) per-channel 8x8 circular-conv kernel KcT[j][c]
//     (blocks 0..7, 32 channels each); (b) hi/lo bf16 split of w_in ->
//     whi/wlo, flat coalesced; (c) bf16 w_out table wob, flat coalesced.
// ---------------------------------------------------------------------------
__global__ void k_precompute(const float* __restrict__ F,
                             const float* __restrict__ w_in,
                             const float* __restrict__ w_out,
                             float* __restrict__ KcT,
                             unsigned short* __restrict__ whi,
                             unsigned short* __restrict__ wlo,
                             unsigned short* __restrict__ wob)
{
    const int tid = threadIdx.x, bid = blockIdx.x;

    // (b) w_in split: flat, coalesced
    for (int e = bid*256 + tid; e < 256*64; e += 16*256) {
        float v = w_in[e];
        unsigned hu = f2bf_bits(v);
        whi[e] = (unsigned short)hu;
        wlo[e] = (unsigned short)f2bf_bits(v - bfbits2f(hu));
    }
    // (c) w_out bf16 table: flat, coalesced
    for (int e = bid*256 + tid; e < 64*128; e += 16*256)
        wob[e] = (unsigned short)f2bf_bits(w_out[e]);

    // (a) conv kernel: blocks 0..7 x threads 0..31 -> one channel each
    if (bid < 8 && tid < 32) {
        const int c = bid*32 + tid;
        const float R = 0.7071067811865476f;
        const float C8[8] = {1.f, R, 0.f, -R, -1.f, -R, 0.f, R};
        const float S8[8] = {0.f, R, 1.f, R, 0.f, -R, -1.f, -R};

        float Fv[8][5];
        for (int u = 0; u < 8; ++u)
            for (int v = 0; v < 5; ++v)
                Fv[u][v] = F[c*40 + u*5 + v];

        float ReG[5][8], ImG[5][8];
        for (int v = 0; v < 5; ++v)
            for (int m = 0; m < 8; ++m) {
                float re = 0.f, im = 0.f;
                for (int u = 0; u < 8; ++u) {
                    int idx = (u*m) & 7;
                    re += Fv[u][v] * C8[idx];
                    im += Fv[u][v] * S8[idx];
                }
                ReG[v][m] = re * 0.125f;
                ImG[v][m] = im * 0.125f;
            }

        for (int m = 0; m < 8; ++m)
            for (int n = 0; n < 8; ++n) {
                float acc = 0.f;
                for (int v = 0; v < 5; ++v) {
                    float wv = (v == 0 || v == 4) ? 0.125f : 0.25f;
                    int idx = (v*n) & 7;
                    acc += wv * (ReG[v][m]*C8[idx] - ImG[v][m]*S8[idx]);
                }
                KcT[(m*8 + n)*256 + c] = acc;        // transposed: [j][channel]
            }
    }
}

// ---------------------------------------------------------------------------
// K1: per (b, h, 64-col run): proj_in via MFMA (m=px16, n=c2, k=cin) with
// hi/lo bf16 split (all 4 nt-tiles accumulated in regs), then VALU circular
// conv (m-outer, coalesced K loads), bf16 chunk-blocked store.
// LDS union (xs region reused by ysT after proj MFMAs) -> 33KB, 4 blocks/CU.
// ---------------------------------------------------------------------------
__global__ __launch_bounds__(256, 4) void k1_proj_circ(
    const float* __restrict__ x,
    const unsigned short* __restrict__ whi,
    const unsigned short* __restrict__ wlo,
    const float* __restrict__ b_in, const float* __restrict__ KcT,
    bf16* __restrict__ s)
{
    // union: [0,4096)hw = xs_hi, [4096,8192)hw = xs_lo during staging+MFMA;
    // whole [0, 64*258)hw = ysT afterwards.
    __shared__ __align__(16) unsigned short smem[64*258];   // 33,024 B
    unsigned short* xs_hi = smem;
    unsigned short* xs_lo = smem + 4096;
    unsigned short* ysT   = smem;

    const int tid = threadIdx.x;
    const int bid = blockIdx.x;
    const int run = bid & 3;
    const int h   = (bid >> 2) & 255;
    const int b   = bid >> 10;

    const float* xb = x + (long)b * CIN * HW + h * WW + run * 64;

    // stage x tile (64 cin x 64 px), hi/lo bf16 split, transposed [px][cin],
    // XOR-swizzled: element (row=px, c) at halfword row*64 + (c ^ ((row&7)<<3)).
#pragma unroll
    for (int i = 0; i < 16; ++i) {
        int e = i*256 + tid;
        int c = e >> 6, col = e & 63;
        float v = xb[(long)c * HW + col];
        unsigned hu = f2bf_bits(v);
        unsigned lu = f2bf_bits(v - bfbits2f(hu));
        const int sw = col*64 + (c ^ ((col & 7) << 3));
        xs_hi[sw] = (unsigned short)hu;
        xs_lo[sw] = (unsigned short)lu;
    }
    __syncthreads();

    const int wv = tid >> 6, lane = tid & 63;
    const int quad = lane >> 4, n16 = lane & 15;

    // proj MFMAs: all 4 nt-tiles, accumulators held in registers.
    f32x4 acc[4][4];
#pragma unroll
    for (int nt = 0; nt < 4; ++nt)
#pragma unroll
        for (int mt = 0; mt < 4; ++mt) acc[nt][mt] = (f32x4){0.f,0.f,0.f,0.f};

#pragma unroll
    for (int nt = 0; nt < 4; ++nt) {
        const int c2 = wv*64 + nt*16 + n16;
#pragma unroll
        for (int k = 0; k < 2; ++k) {
            const bf16x8 bh = *(const bf16x8*)&whi[c2*64 + k*32 + quad*8];
            const bf16x8 bl = *(const bf16x8*)&wlo[c2*64 + k*32 + quad*8];
#pragma unroll
            for (int mt = 0; mt < 4; ++mt) {
                // row = mt*16+n16; 16B slot (k*4+quad) XOR (row&7)
                const int o = (mt*16 + n16)*64 + (((k*4 + quad) ^ (n16 & 7)) << 3);
                const bf16x8 a_h = *(const bf16x8*)&xs_hi[o];
                const bf16x8 a_l = *(const bf16x8*)&xs_lo[o];
                acc[nt][mt] = __builtin_amdgcn_mfma_f32_16x16x32_bf16(a_h, bh, acc[nt][mt], 0, 0, 0);
                acc[nt][mt] = __builtin_amdgcn_mfma_f32_16x16x32_bf16(a_l, bh, acc[nt][mt], 0, 0, 0);
                acc[nt][mt] = __builtin_amdgcn_mfma_f32_16x16x32_bf16(a_h, bl, acc[nt][mt], 0, 0, 0);
            }
        }
    }
    __syncthreads();        // xs region dead; safe to overwrite with ysT

    // write ysT[u][c2] (stride 258) + bias
#pragma unroll
    for (int nt = 0; nt < 4; ++nt) {
        const int c2 = wv*64 + nt*16 + n16;
        const float bv = b_in[c2];
#pragma unroll
        for (int mt = 0; mt < 4; ++mt)
#pragma unroll
            for (int r = 0; r < 4; ++r) {
                int u = mt*16 + quad*4 + r;          // D row = quad*4 + reg
                ysT[u*258 + c2] = (unsigned short)f2bf_bits(acc[nt][mt][r] + bv);
            }
    }
    __syncthreads();

    // circular conv: thread = channel tid. Column tid of ysT is private to
    // this thread (reads and writes), so no barrier needed inside.
    // m-OUTER rolled loop: K row m loaded once, lane-coalesced from KcT.
    float o[64];
#pragma unroll
    for (int i = 0; i < 64; ++i) o[i] = 0.f;

    for (int m = 0; m < 8; ++m) {                    // rolled: keeps code small
        float kk[8];
#pragma unroll
        for (int n = 0; n < 8; ++n)
            kk[n] = KcT[(m*8 + n)*256 + tid];        // 64 lanes x 4B contiguous
#pragma unroll
        for (int a = 0; a < 8; ++a) {
            const int r = (a - m) & 7;
            float yy[8];
#pragma unroll
            for (int q = 0; q < 8; ++q)
                yy[q] = bfbits2f((unsigned)ysT[(r*8 + q)*258 + tid]);
#pragma unroll
            for (int n = 0; n < 8; ++n)
#pragma unroll
                for (int bb = 0; bb < 8; ++bb)
                    o[a*8 + bb] += kk[n] * yy[(bb - n) & 7];
        }
    }

#pragma unroll
    for (int u = 0; u < 64; ++u)
        ysT[u*258 + tid] = (unsigned short)f2bf_bits(o[u]);
    __syncthreads();

    // store: chunk-blocked layout s[b][chunk=c2/8][h][w][8ch]
    // lane = px u -> 64 lanes x 16B = 1KB contiguous per (chunk, pass).
    const int u   = tid & 63;
    const int rg2 = tid >> 6;          // 0..3
#pragma unroll
    for (int pass = 0; pass < 8; ++pass) {
        const int chunk = pass*4 + rg2;                       // 0..31
        const unsigned* yp = (const unsigned*)&ysT[u*258 + chunk*8];
        uint4 val = make_uint4(yp[0], yp[1], yp[2], yp[3]);
        *(uint4*)(s + ((((long)(b*32 + chunk)*HH + h)*WW) + run*64 + u)*8) = val;
    }
}

// ---------------------------------------------------------------------------
// K2: per (b, h, run of 64 px): dw3x3 + bias -> GELU gate -> MFMA proj_out.
// Phase 1: thread = (px=lane, chunk-pair of 8 ch), 4 tasks; 18 x 16B global
//   loads per task, fully coalesced (chunk wave-uniform, wx lane-consecutive
//   -> 1KB/wave-load); g packed bf16 into LDS gs[px][c] stride 136.
// Phase 2: MFMA 16x16x32_bf16, m=c_out(64), n=px(64), k=c(128). Wave rg owns
//   px-tile rg*16; A-frags from ws-resident wob table, B-frags ds_read_b128.
// ---------------------------------------------------------------------------
__global__ __launch_bounds__(256) void k2_dw_gelu_out(
    const bf16* __restrict__ s, const float* __restrict__ w_dw,
    const float* __restrict__ b_dw,
    const unsigned short* __restrict__ wob,
    const float* __restrict__ b_out, float* __restrict__ out)
{
    __shared__ __align__(16) unsigned short gs[64*136];   // 17 KB, [px][c]

    const int tid = threadIdx.x;
    const int l   = ((blockIdx.x & 7) << 9) | (blockIdx.x >> 3);  // XCD swizzle
    const int run = l & 3;
    const int h   = (l >> 2) & 255;
    const int b   = l >> 10;
    const int wl  = tid & 63, rg = tid >> 6;
    const int w   = run*64 + wl;

#pragma unroll
    for (int i = 0; i < 4; ++i) {
        const int chunk = __builtin_amdgcn_readfirstlane(rg + 4*i);   // 0..15, uniform
        const int c0 = chunk*8;                                        // 0..120
        const bf16* pb1 = s + (long)(b*32 + chunk     ) * HW * 8;
        const bf16* pb2 = s + (long)(b*32 + chunk + 16) * HW * 8;

        float t1[8], t2[8];
#pragma unroll
        for (int j = 0; j < 8; ++j) { t1[j] = b_dw[c0+j]; t2[j] = b_dw[c0+128+j]; }

#pragma unroll
        for (int dy = 0; dy < 3; ++dy) {
            const int hy = h + dy - 1;
            if ((unsigned)hy >= HH) continue;          // wave-uniform
#pragma unroll
            for (int dx = 0; dx < 3; ++dx) {
                const int wx = w + dx - 1;
                if ((unsigned)wx < WW) {               // diverges only at image edge
                    const int off = (hy*WW + wx) << 3; // element offset, fits int
                    uint4 v1 = *(const uint4*)(pb1 + off);
                    uint4 v2 = *(const uint4*)(pb2 + off);
                    float f1[8], f2[8];
                    unpack8(v1, f1); unpack8(v2, f2);
#pragma unroll
                    for (int j = 0; j < 8; ++j) {
                        t1[j] += f1[j] * w_dw[(c0+j)*9       + dy*3 + dx];
                        t2[j] += f2[j] * w_dw[(c0+128+j)*9   + dy*3 + dx];
                    }
                }
            }
        }
        // GELU(t1)*t2 (poly erf); pack to bf16 pairs, store [px=wl][c0..c0+7]
        unsigned r4[4];
#pragma unroll
        for (int j = 0; j < 4; ++j) {
            float ga = gelu_exact(t1[2*j])   * t2[2*j];
            float gb = gelu_exact(t1[2*j+1]) * t2[2*j+1];
            r4[j] = f2bf_bits(ga) | (f2bf_bits(gb) << 16);
        }
        *(uint4*)&gs[wl*136 + c0] = make_uint4(r4[0], r4[1], r4[2], r4[3]);
    }
    __syncthreads();

    // Phase 2: MFMA proj_out. Wave rg -> px-tile rg*16..+15.
    const int quad = wl >> 4, n16 = wl & 15;
    const int px   = rg*16 + n16;

    f32x4 acc[4];                                  // mt = c_out tile
#pragma unroll
    for (int mt = 0; mt < 4; ++mt) acc[mt] = (f32x4){0.f,0.f,0.f,0.f};

#pragma unroll
    for (int ks = 0; ks < 4; ++ks) {
        const bf16x8 bfrag = *(const bf16x8*)&gs[px*136 + ks*32 + quad*8];
#pragma unroll
        for (int mt = 0; mt < 4; ++mt) {
            const bf16x8 afrag = *(const bf16x8*)&wob[(mt*16 + n16)*128 + ks*32 + quad*8];
            acc[mt] = __builtin_amdgcn_mfma_f32_16x16x32_bf16(afrag, bfrag, acc[mt], 0, 0, 0);
        }
    }

    // D: col=lane&15 = n = px-within-tile, row = quad*4+r = c_out-within-tile
    float* op = out + (long)b * CIN * HW + h * WW + run*64 + rg*16 + n16;
#pragma unroll
    for (int mt = 0; mt < 4; ++mt)
#pragma unroll
        for (int r = 0; r < 4; ++r) {
            const int c_out = mt*16 + quad*4 + r;
            op[(long)c_out * HW] = acc[mt][r] + b_out[c_out];
        }
}

// ---------------------------------------------------------------------------
extern "C" void kernel_launch(void* const* d_in, const int* in_sizes, int n_in,
                              void* d_out, int out_size, void* d_ws, size_t ws_size,
                              hipStream_t stream) {
    const float* x     = (const float*)d_in[0];
    const float* w_in  = (const float*)d_in[1];
    const float* b_in  = (const float*)d_in[2];
    const float* ff    = (const float*)d_in[3];
    const float* w_dw  = (const float*)d_in[4];
    const float* b_dw  = (const float*)d_in[5];
    const float* w_out = (const float*)d_in[6];
    const float* b_out = (const float*)d_in[7];
    float* out = (float*)d_out;

    // d_ws layout: KcT [0,64K) | wob [64K,80K) | s [80K, +128MB)
    float*          KcT = (float*)d_ws;
    unsigned short* wob = (unsigned short*)((char*)d_ws + 65536);   // 16 KB
    bf16*           s   = (bf16*)((char*)d_ws + 65536 + 16384);

    // whi/wlo in d_out is safe: only k1 reads them, and k1 fully retires
    // (stream order) before k2 begins overwriting d_out.
    unsigned short* whi = (unsigned short*)d_out;       // 32 KB
    unsigned short* wlo = whi + 256*64;                 // 32 KB

    hipLaunchKernelGGL(k_precompute,   dim3(16),   dim3(256), 0, stream,
                       ff, w_in, w_out, KcT, whi, wlo, wob);
    hipLaunchKernelGGL(k1_proj_circ,   dim3(4096), dim3(256), 0, stream,
                       x, whi, wlo, b_in, KcT, s);
    hipLaunchKernelGGL(k2_dw_gelu_out, dim3(4096), dim3(256), 0, stream,
                       s, w_dw, b_dw, wob, b_out, out);
}